// Round 1
// baseline (686.780 us; speedup 1.0000x reference)
//
#include <hip/hip_runtime.h>
#include <math.h>

#define NFEAT 128
#define NCLS 40

// ---------------- CSR build ----------------
__global__ void zero_int(int* __restrict__ p, int n) {
  int i = blockIdx.x * 256 + threadIdx.x;
  if (i < n) p[i] = 0;
}

__global__ void count_deg(const int* __restrict__ ei, int* __restrict__ deg, int e) {
  int i = blockIdx.x * 256 + threadIdx.x;
  if (i < e) atomicAdd(&deg[ei[e + i]], 1);   // ei[e+i] = dst row of edge_index
}

__global__ __launch_bounds__(1024) void scan_block(const int* __restrict__ deg,
    int* __restrict__ offs, int* __restrict__ partials, int n) {
  __shared__ int s[1024];
  int t = threadIdx.x;
  int i = blockIdx.x * 1024 + t;
  int v = (i < n) ? deg[i] : 0;
  s[t] = v;
  __syncthreads();
  int val = v;
  for (int d = 1; d < 1024; d <<= 1) {
    int other = (t >= d) ? s[t - d] : 0;
    __syncthreads();
    val += other;
    s[t] = val;
    __syncthreads();
  }
  if (i < n) offs[i] = val - v;              // exclusive within block
  if (t == 1023) partials[blockIdx.x] = val; // block total
}

__global__ void scan_partials(int* __restrict__ partials, int nb) {
  if (threadIdx.x == 0 && blockIdx.x == 0) {
    int acc = 0;
    for (int b = 0; b < nb; b++) { int v = partials[b]; partials[b] = acc; acc += v; }
  }
}

__global__ void scan_add(int* __restrict__ offs, const int* __restrict__ partials,
    int* __restrict__ cursor, int n, int e) {
  int i = blockIdx.x * 256 + threadIdx.x;
  if (i < n) {
    int o = offs[i] + partials[i >> 10];
    offs[i] = o;
    cursor[i] = o;
  } else if (i == n) {
    offs[n] = e;
  }
}

__global__ void build_csr(const int* __restrict__ ei, const float* __restrict__ ew,
    int* __restrict__ cursor, int2* __restrict__ cedge, int e) {
  int i = blockIdx.x * 256 + threadIdx.x;
  if (i < e) {
    int s = ei[i];
    int d = ei[e + i];
    int p = atomicAdd(&cursor[d], 1);
    cedge[p] = make_int2(s, __float_as_int(ew[i]));
  }
}

// ---------------- dense GEMM: Y[n,128] = X[n,128] @ W[128,128] ----------------
#define GB_M 32
#define GB_KC 64
__global__ __launch_bounds__(256) void gemm128(const float* __restrict__ X,
    const float* __restrict__ W, float* __restrict__ Y, int n) {
  __shared__ float Xs[GB_KC][GB_M + 4];   // transposed: Xs[k][r]
  __shared__ float Ws[GB_KC][128 + 4];
  int t = threadIdx.x;
  int tx = t & 31, ty = t >> 5;           // cols tx*4.., rows ty*4..
  int row0 = blockIdx.x * GB_M;
  float acc[4][4] = {};
  for (int kc = 0; kc < 128; kc += GB_KC) {
    { // stage X tile (32 rows x 64 k), transposed into LDS
      int r = t & 31;
      int k0 = (t >> 5) * 8;
      int row = row0 + r;
      if (row < n) {
        const float4* src = (const float4*)(X + (size_t)row * 128 + kc + k0);
        float4 v0 = src[0], v1 = src[1];
        Xs[k0+0][r]=v0.x; Xs[k0+1][r]=v0.y; Xs[k0+2][r]=v0.z; Xs[k0+3][r]=v0.w;
        Xs[k0+4][r]=v1.x; Xs[k0+5][r]=v1.y; Xs[k0+6][r]=v1.z; Xs[k0+7][r]=v1.w;
      } else {
        #pragma unroll
        for (int i = 0; i < 8; i++) Xs[k0+i][r] = 0.f;
      }
    }
    { // stage W tile (64 k x 128 cols), coalesced
      int k = t >> 2;
      int j0 = (t & 3) * 32;
      const float4* src = (const float4*)(W + (size_t)(kc + k) * 128 + j0);
      float4* dst = (float4*)&Ws[k][j0];
      #pragma unroll
      for (int i = 0; i < 8; i++) dst[i] = src[i];
    }
    __syncthreads();
    #pragma unroll 4
    for (int k = 0; k < GB_KC; k++) {
      float4 a = *(const float4*)&Xs[k][ty * 4];
      float4 b = *(const float4*)&Ws[k][tx * 4];
      acc[0][0]=fmaf(a.x,b.x,acc[0][0]); acc[0][1]=fmaf(a.x,b.y,acc[0][1]);
      acc[0][2]=fmaf(a.x,b.z,acc[0][2]); acc[0][3]=fmaf(a.x,b.w,acc[0][3]);
      acc[1][0]=fmaf(a.y,b.x,acc[1][0]); acc[1][1]=fmaf(a.y,b.y,acc[1][1]);
      acc[1][2]=fmaf(a.y,b.z,acc[1][2]); acc[1][3]=fmaf(a.y,b.w,acc[1][3]);
      acc[2][0]=fmaf(a.z,b.x,acc[2][0]); acc[2][1]=fmaf(a.z,b.y,acc[2][1]);
      acc[2][2]=fmaf(a.z,b.z,acc[2][2]); acc[2][3]=fmaf(a.z,b.w,acc[2][3]);
      acc[3][0]=fmaf(a.w,b.x,acc[3][0]); acc[3][1]=fmaf(a.w,b.y,acc[3][1]);
      acc[3][2]=fmaf(a.w,b.z,acc[3][2]); acc[3][3]=fmaf(a.w,b.w,acc[3][3]);
    }
    __syncthreads();
  }
  #pragma unroll
  for (int i = 0; i < 4; i++) {
    int row = row0 + ty * 4 + i;
    if (row < n) {
      float4 v = make_float4(acc[i][0], acc[i][1], acc[i][2], acc[i][3]);
      *(float4*)(Y + (size_t)row * 128 + tx * 4) = v;
    }
  }
}

// -------- SpMM + self + bias + ReLU: H[n] = relu(Y[n] + sum_e w*Y[src] + b) --------
__global__ __launch_bounds__(256) void spmm_relu(const float* __restrict__ Y,
    const int* __restrict__ offs, const int2* __restrict__ cedge,
    const float* __restrict__ bias, float* __restrict__ H, int n) {
  int wv = threadIdx.x >> 6;
  int lane = threadIdx.x & 63;
  int node = blockIdx.x * 4 + wv;          // one wave per dst node
  if (node >= n) return;
  int c = lane * 2;                        // 2 channels per lane -> 512B/wave gathers
  int e0 = offs[node], e1 = offs[node + 1];
  float ax0 = 0.f, ay0 = 0.f, ax1 = 0.f, ay1 = 0.f;
  int e = e0;
  for (; e + 1 < e1; e += 2) {             // 2-way unroll: two gathers in flight
    int2 p0 = cedge[e];
    int2 p1 = cedge[e + 1];
    float2 v0 = *(const float2*)(Y + (size_t)p0.x * 128 + c);
    float2 v1 = *(const float2*)(Y + (size_t)p1.x * 128 + c);
    float w0 = __int_as_float(p0.y), w1 = __int_as_float(p1.y);
    ax0 = fmaf(w0, v0.x, ax0); ay0 = fmaf(w0, v0.y, ay0);
    ax1 = fmaf(w1, v1.x, ax1); ay1 = fmaf(w1, v1.y, ay1);
  }
  if (e < e1) {
    int2 p0 = cedge[e];
    float2 v0 = *(const float2*)(Y + (size_t)p0.x * 128 + c);
    float w0 = __int_as_float(p0.y);
    ax0 = fmaf(w0, v0.x, ax0); ay0 = fmaf(w0, v0.y, ay0);
  }
  float2 yv = *(const float2*)(Y + (size_t)node * 128 + c);
  float2 bv = *(const float2*)(bias + c);
  float zx = yv.x + ax0 + ax1 + bv.x;
  float zy = yv.y + ay0 + ay1 + bv.y;
  float2 o; o.x = fmaxf(zx, 0.f); o.y = fmaxf(zy, 0.f);
  *(float2*)(H + (size_t)node * 128 + c) = o;
}

// -------- FC over concat(h1,h2) + log_softmax, fused --------
__global__ __launch_bounds__(256) void fc_lsm(const float* __restrict__ H1,
    const float* __restrict__ H2, const float* __restrict__ Wfc,
    const float* __restrict__ bfc, float* __restrict__ out, int n) {
  __shared__ float Wl[256 * NCLS];        // 40 KB, [k][c] layout, stride 40
  __shared__ float Hs[64][132];           // 33 KB, transposed chunk Hs[k][r]
  int t = threadIdx.x;
  for (int i = t; i < 256 * NCLS; i += 256) Wl[i] = Wfc[i];
  int tx = t & 7, ty = t >> 3;            // tx: 5-col group (8x5=40), ty: 4-row group (32x4=128)
  int row0 = blockIdx.x * 128;
  float acc[4][5] = {};
  for (int kc = 0; kc < 256; kc += 64) {
    { // stage 128 rows x 64 k of concat(H1,H2), transposed
      int r = t & 127;
      int half = t >> 7;                  // k sub-offset 0/32
      int row = row0 + r;
      const float* src = (kc < 128) ? (H1 + (size_t)row * 128 + kc + half * 32)
                                    : (H2 + (size_t)row * 128 + (kc - 128) + half * 32);
      if (row < n) {
        #pragma unroll
        for (int i = 0; i < 8; i++) {
          float4 v = ((const float4*)src)[i];
          Hs[half*32 + i*4 + 0][r] = v.x;
          Hs[half*32 + i*4 + 1][r] = v.y;
          Hs[half*32 + i*4 + 2][r] = v.z;
          Hs[half*32 + i*4 + 3][r] = v.w;
        }
      } else {
        #pragma unroll
        for (int k = 0; k < 32; k++) Hs[half*32 + k][r] = 0.f;
      }
    }
    __syncthreads();
    #pragma unroll 4
    for (int k = 0; k < 64; k++) {
      float4 a = *(const float4*)&Hs[k][ty * 4];
      const float* wrow = &Wl[(kc + k) * NCLS + tx * 5];
      float b_[5];
      #pragma unroll
      for (int j = 0; j < 5; j++) b_[j] = wrow[j];
      #pragma unroll
      for (int j = 0; j < 5; j++) {
        acc[0][j] = fmaf(a.x, b_[j], acc[0][j]);
        acc[1][j] = fmaf(a.y, b_[j], acc[1][j]);
        acc[2][j] = fmaf(a.z, b_[j], acc[2][j]);
        acc[3][j] = fmaf(a.w, b_[j], acc[3][j]);
      }
    }
    __syncthreads();
  }
  int c0 = tx * 5;
  float bv[5];
  #pragma unroll
  for (int j = 0; j < 5; j++) bv[j] = bfc[c0 + j];
  #pragma unroll
  for (int i = 0; i < 4; i++) {
    float lg[5];
    #pragma unroll
    for (int j = 0; j < 5; j++) lg[j] = acc[i][j] + bv[j];
    float m = lg[0];
    #pragma unroll
    for (int j = 1; j < 5; j++) m = fmaxf(m, lg[j]);
    m = fmaxf(m, __shfl_xor(m, 1));
    m = fmaxf(m, __shfl_xor(m, 2));
    m = fmaxf(m, __shfl_xor(m, 4));       // 8 lanes (same ty) own one row's 40 cols
    float ssum = 0.f;
    #pragma unroll
    for (int j = 0; j < 5; j++) ssum += __expf(lg[j] - m);
    ssum += __shfl_xor(ssum, 1);
    ssum += __shfl_xor(ssum, 2);
    ssum += __shfl_xor(ssum, 4);
    float lse = m + __logf(ssum);
    int row = row0 + ty * 4 + i;
    if (row < n) {
      #pragma unroll
      for (int j = 0; j < 5; j++) out[(size_t)row * NCLS + c0 + j] = lg[j] - lse;
    }
  }
}

extern "C" void kernel_launch(void* const* d_in, const int* in_sizes, int n_in,
                              void* d_out, int out_size, void* d_ws, size_t ws_size,
                              hipStream_t stream) {
  const float* x   = (const float*)d_in[0];
  const int*   ei  = (const int*)d_in[1];
  const float* ew  = (const float*)d_in[2];
  const float* W1  = (const float*)d_in[3];
  const float* b1  = (const float*)d_in[4];
  const float* W2  = (const float*)d_in[5];
  const float* b2  = (const float*)d_in[6];
  const float* Wfc = (const float*)d_in[7];
  const float* bfc = (const float*)d_in[8];
  float* out = (float*)d_out;
  int n = in_sizes[0] / NFEAT;   // 100000
  int e = in_sizes[2];           // 1600000

  // workspace partition (~167 MB total)
  char* ws = (char*)d_ws;
  size_t off = 0;
  auto alloc = [&](size_t bytes) -> void* {
    void* p = ws + off; off += (bytes + 255) & ~(size_t)255; return p;
  };
  int*   deg      = (int*)alloc((size_t)n * 4);
  int*   offs     = (int*)alloc((size_t)(n + 1) * 4);
  int*   cursor   = (int*)alloc((size_t)n * 4);
  int*   partials = (int*)alloc(1024 * 4);
  int2*  cedge    = (int2*)alloc((size_t)e * 8);
  float* y        = (float*)alloc((size_t)n * 128 * 4);
  float* h1       = (float*)alloc((size_t)n * 128 * 4);
  float* h2       = (float*)alloc((size_t)n * 128 * 4);

  int eb = (e + 255) / 256;
  int nb = (n + 1023) / 1024;

  // CSR build
  zero_int<<<(n + 255) / 256, 256, 0, stream>>>(deg, n);
  count_deg<<<eb, 256, 0, stream>>>(ei, deg, e);
  scan_block<<<nb, 1024, 0, stream>>>(deg, offs, partials, n);
  scan_partials<<<1, 64, 0, stream>>>(partials, nb);
  scan_add<<<(n + 256) / 256, 256, 0, stream>>>(offs, partials, cursor, n, e);
  build_csr<<<eb, 256, 0, stream>>>(ei, ew, cursor, cedge, e);

  // layer 1: y = x@W1 ; h1 = relu(y + A y + b1)
  gemm128<<<(n + GB_M - 1) / GB_M, 256, 0, stream>>>(x, W1, y, n);
  spmm_relu<<<(n + 3) / 4, 256, 0, stream>>>(y, offs, cedge, b1, h1, n);
  // layer 2: y = h1@W2 ; h2 = relu(y + A y + b2)
  gemm128<<<(n + GB_M - 1) / GB_M, 256, 0, stream>>>(h1, W2, y, n);
  spmm_relu<<<(n + 3) / 4, 256, 0, stream>>>(y, offs, cedge, b2, h2, n);
  // FC + log_softmax
  fc_lsm<<<(n + 127) / 128, 256, 0, stream>>>(h1, h2, Wfc, bfc, out, n);
}

// Round 2
// 644.974 us; speedup vs baseline: 1.0648x; 1.0648x over previous
//
#include <hip/hip_runtime.h>
#include <math.h>

#define NFEAT 128
#define NCLS 40

using f16x8 = __attribute__((ext_vector_type(8))) _Float16;
using f16x2 = __attribute__((ext_vector_type(2))) _Float16;
using f32x4 = __attribute__((ext_vector_type(4))) float;

// ---------------- CSR build ----------------
__global__ void zero_int(int* __restrict__ p, int n) {
  int i = blockIdx.x * 256 + threadIdx.x;
  if (i < n) p[i] = 0;
}

__global__ void count_deg(const int* __restrict__ ei, int* __restrict__ deg, int e) {
  int i = blockIdx.x * 256 + threadIdx.x;
  if (i < e) atomicAdd(&deg[ei[e + i]], 1);   // ei[e+i] = dst row of edge_index
}

__global__ __launch_bounds__(1024) void scan_block(const int* __restrict__ deg,
    int* __restrict__ offs, int* __restrict__ partials, int n) {
  __shared__ int s[1024];
  int t = threadIdx.x;
  int i = blockIdx.x * 1024 + t;
  int v = (i < n) ? deg[i] : 0;
  s[t] = v;
  __syncthreads();
  int val = v;
  for (int d = 1; d < 1024; d <<= 1) {
    int other = (t >= d) ? s[t - d] : 0;
    __syncthreads();
    val += other;
    s[t] = val;
    __syncthreads();
  }
  if (i < n) offs[i] = val - v;              // exclusive within block
  if (t == 1023) partials[blockIdx.x] = val; // block total
}

__global__ __launch_bounds__(128) void scan_partials(int* __restrict__ partials, int nb) {
  // parallel exclusive scan over <=128 block totals (was a serial 1-thread loop)
  __shared__ int s[128];
  int t = threadIdx.x;
  int v = (t < nb) ? partials[t] : 0;
  s[t] = v;
  __syncthreads();
  int val = v;
  for (int d = 1; d < 128; d <<= 1) {
    int other = (t >= d) ? s[t - d] : 0;
    __syncthreads();
    val += other;
    s[t] = val;
    __syncthreads();
  }
  if (t < nb) partials[t] = val - v;
}

__global__ void scan_add(int* __restrict__ offs, const int* __restrict__ partials,
    int* __restrict__ cursor, int n, int e) {
  int i = blockIdx.x * 256 + threadIdx.x;
  if (i < n) {
    int o = offs[i] + partials[i >> 10];
    offs[i] = o;
    cursor[i] = o;
  } else if (i == n) {
    offs[n] = e;
  }
}

__global__ void build_csr(const int* __restrict__ ei, const float* __restrict__ ew,
    int* __restrict__ cursor, int2* __restrict__ cedge, int e) {
  int i = blockIdx.x * 256 + threadIdx.x;
  if (i < e) {
    int s = ei[i];
    int d = ei[e + i];
    int p = atomicAdd(&cursor[d], 1);
    cedge[p] = make_int2(s, __float_as_int(ew[i]));
  }
}

// ---------------- fp32 -> fp16 converts ----------------
__global__ void convert_f16(const float* __restrict__ X, _Float16* __restrict__ Xh, int n4) {
  int i = blockIdx.x * 256 + threadIdx.x;
  if (i < n4) {
    float4 v = ((const float4*)X)[i];
    f16x2 a, b;
    a.x = (_Float16)v.x; a.y = (_Float16)v.y;
    b.x = (_Float16)v.z; b.y = (_Float16)v.w;
    ((f16x2*)Xh)[i * 2] = a;
    ((f16x2*)Xh)[i * 2 + 1] = b;
  }
}

__global__ void convert_wt(const float* __restrict__ W, _Float16* __restrict__ Wt) {
  // Wt[c][k] = fp16(W[k][c]), 128x128
  int t = threadIdx.x;
  for (int i = t; i < 128 * 128; i += 256) {
    int c = i >> 7, k = i & 127;
    Wt[i] = (_Float16)W[k * 128 + c];
  }
}

// ------- MFMA GEMM: Y[n,128](f16) = Xh[n,128](f16) @ W (Wt = W^T, f16) -------
// 4 waves/block, each wave: 16 rows x 128 cols, mfma_f32_16x16x32_f16.
// A frag: row = lane&15, k = (lane>>4)*8 + j (8 contiguous).  B frag from Wt[col][k].
// C/D: col = lane&15, row = (lane>>4)*4 + reg.
__global__ __launch_bounds__(256) void gemm_f16(const _Float16* __restrict__ Xh,
    const _Float16* __restrict__ Wt, _Float16* __restrict__ Y, int n) {
  __shared__ _Float16 Ys[64][136];   // bounce for coalesced stores (272B row, 16B-aligned)
  int t = threadIdx.x;
  int wv = t >> 6, l = t & 63;
  int r0 = blockIdx.x * 64 + wv * 16;
  int arow = r0 + (l & 15);
  int kq = (l >> 4) * 8;
  bool rowok = arow < n;
  f32x4 acc[8] = {};
  for (int kc = 0; kc < 128; kc += 32) {
    f16x8 a = {};
    if (rowok) a = *(const f16x8*)(Xh + (size_t)arow * 128 + kc + kq);
    #pragma unroll
    for (int j = 0; j < 8; j++) {
      f16x8 b = *(const f16x8*)(Wt + (size_t)(j * 16 + (l & 15)) * 128 + kc + kq);
      acc[j] = __builtin_amdgcn_mfma_f32_16x16x32_f16(a, b, acc[j], 0, 0, 0);
    }
  }
  #pragma unroll
  for (int j = 0; j < 8; j++)
    #pragma unroll
    for (int i = 0; i < 4; i++)
      Ys[wv * 16 + (l >> 4) * 4 + i][j * 16 + (l & 15)] = (_Float16)acc[j][i];
  __syncthreads();
  int r = t >> 2;
  int c0 = (t & 3) * 32;
  int grow = blockIdx.x * 64 + r;
  if (grow < n) {
    #pragma unroll
    for (int i = 0; i < 4; i++) {
      f16x8 v = *(const f16x8*)&Ys[r][c0 + i * 8];
      *(f16x8*)(Y + (size_t)grow * 128 + c0 + i * 8) = v;
    }
  }
}

// -- SpMM + self + bias + ReLU (fp16 rows, fp32 accum): H = relu(Y + A Y + b) --
__global__ __launch_bounds__(256) void spmm_relu_f16(const _Float16* __restrict__ Y,
    const int* __restrict__ offs, const int2* __restrict__ cedge,
    const float* __restrict__ bias, _Float16* __restrict__ H, int n) {
  int wv = threadIdx.x >> 6;
  int lane = threadIdx.x & 63;
  int node = blockIdx.x * 4 + wv;          // one wave per dst node
  if (node >= n) return;
  int c = lane * 2;                        // 2 channels/lane -> 256B/wave gathers
  int e0 = offs[node], e1 = offs[node + 1];
  float ax0 = 0.f, ay0 = 0.f, ax1 = 0.f, ay1 = 0.f;
  int e = e0;
  for (; e + 1 < e1; e += 2) {             // 2 gathers in flight
    int2 p0 = cedge[e];
    int2 p1 = cedge[e + 1];
    f16x2 v0 = *(const f16x2*)(Y + (size_t)p0.x * 128 + c);
    f16x2 v1 = *(const f16x2*)(Y + (size_t)p1.x * 128 + c);
    float w0 = __int_as_float(p0.y), w1 = __int_as_float(p1.y);
    ax0 = fmaf(w0, (float)v0.x, ax0); ay0 = fmaf(w0, (float)v0.y, ay0);
    ax1 = fmaf(w1, (float)v1.x, ax1); ay1 = fmaf(w1, (float)v1.y, ay1);
  }
  if (e < e1) {
    int2 p0 = cedge[e];
    f16x2 v0 = *(const f16x2*)(Y + (size_t)p0.x * 128 + c);
    float w0 = __int_as_float(p0.y);
    ax0 = fmaf(w0, (float)v0.x, ax0); ay0 = fmaf(w0, (float)v0.y, ay0);
  }
  f16x2 yv = *(const f16x2*)(Y + (size_t)node * 128 + c);
  float2 bv = *(const float2*)(bias + c);
  float zx = (float)yv.x + ax0 + ax1 + bv.x;
  float zy = (float)yv.y + ay0 + ay1 + bv.y;
  f16x2 o;
  o.x = (_Float16)fmaxf(zx, 0.f);
  o.y = (_Float16)fmaxf(zy, 0.f);
  *(f16x2*)(H + (size_t)node * 128 + c) = o;
}

// -------- FC over concat(h1,h2)(f16) + log_softmax (fp32 compute) --------
__global__ __launch_bounds__(256) void fc_lsm(const _Float16* __restrict__ H1,
    const _Float16* __restrict__ H2, const float* __restrict__ Wfc,
    const float* __restrict__ bfc, float* __restrict__ out, int n) {
  __shared__ float Wl[256 * NCLS];        // 40 KB, [k][c] layout
  __shared__ float Hs[64][132];           // 33 KB, transposed chunk Hs[k][r]
  int t = threadIdx.x;
  for (int i = t; i < 256 * NCLS; i += 256) Wl[i] = Wfc[i];
  int tx = t & 7, ty = t >> 3;            // tx: 5-col group (8x5=40), ty: 4-row group
  int row0 = blockIdx.x * 128;
  float acc[4][5] = {};
  for (int kc = 0; kc < 256; kc += 64) {
    { // stage 128 rows x 64 k of concat(H1,H2), transposed, f16 -> f32
      int r = t & 127;
      int half = t >> 7;
      int row = row0 + r;
      const _Float16* src = (kc < 128)
          ? (H1 + (size_t)row * 128 + kc + half * 32)
          : (H2 + (size_t)row * 128 + (kc - 128) + half * 32);
      if (row < n) {
        #pragma unroll
        for (int i = 0; i < 4; i++) {
          f16x8 v = ((const f16x8*)src)[i];
          #pragma unroll
          for (int q = 0; q < 8; q++) Hs[half * 32 + i * 8 + q][r] = (float)v[q];
        }
      } else {
        #pragma unroll
        for (int k = 0; k < 32; k++) Hs[half * 32 + k][r] = 0.f;
      }
    }
    __syncthreads();
    #pragma unroll 4
    for (int k = 0; k < 64; k++) {
      float4 a = *(const float4*)&Hs[k][ty * 4];
      const float* wrow = &Wl[(kc + k) * NCLS + tx * 5];
      float b_[5];
      #pragma unroll
      for (int j = 0; j < 5; j++) b_[j] = wrow[j];
      #pragma unroll
      for (int j = 0; j < 5; j++) {
        acc[0][j] = fmaf(a.x, b_[j], acc[0][j]);
        acc[1][j] = fmaf(a.y, b_[j], acc[1][j]);
        acc[2][j] = fmaf(a.z, b_[j], acc[2][j]);
        acc[3][j] = fmaf(a.w, b_[j], acc[3][j]);
      }
    }
    __syncthreads();
  }
  int c0 = tx * 5;
  float bv[5];
  #pragma unroll
  for (int j = 0; j < 5; j++) bv[j] = bfc[c0 + j];
  #pragma unroll
  for (int i = 0; i < 4; i++) {
    float lg[5];
    #pragma unroll
    for (int j = 0; j < 5; j++) lg[j] = acc[i][j] + bv[j];
    float m = lg[0];
    #pragma unroll
    for (int j = 1; j < 5; j++) m = fmaxf(m, lg[j]);
    m = fmaxf(m, __shfl_xor(m, 1));
    m = fmaxf(m, __shfl_xor(m, 2));
    m = fmaxf(m, __shfl_xor(m, 4));       // 8 lanes (same ty) own one row's 40 cols
    float ssum = 0.f;
    #pragma unroll
    for (int j = 0; j < 5; j++) ssum += __expf(lg[j] - m);
    ssum += __shfl_xor(ssum, 1);
    ssum += __shfl_xor(ssum, 2);
    ssum += __shfl_xor(ssum, 4);
    float lse = m + __logf(ssum);
    int row = row0 + ty * 4 + i;
    if (row < n) {
      #pragma unroll
      for (int j = 0; j < 5; j++) out[(size_t)row * NCLS + c0 + j] = lg[j] - lse;
    }
  }
}

extern "C" void kernel_launch(void* const* d_in, const int* in_sizes, int n_in,
                              void* d_out, int out_size, void* d_ws, size_t ws_size,
                              hipStream_t stream) {
  const float* x   = (const float*)d_in[0];
  const int*   ei  = (const int*)d_in[1];
  const float* ew  = (const float*)d_in[2];
  const float* W1  = (const float*)d_in[3];
  const float* b1  = (const float*)d_in[4];
  const float* W2  = (const float*)d_in[5];
  const float* b2  = (const float*)d_in[6];
  const float* Wfc = (const float*)d_in[7];
  const float* bfc = (const float*)d_in[8];
  float* out = (float*)d_out;
  int n = in_sizes[0] / NFEAT;   // 100000
  int e = in_sizes[2];           // 1600000

  // workspace partition (~116 MB)
  char* ws = (char*)d_ws;
  size_t off = 0;
  auto alloc = [&](size_t bytes) -> void* {
    void* p = ws + off; off += (bytes + 255) & ~(size_t)255; return p;
  };
  int*      deg      = (int*)alloc((size_t)n * 4);
  int*      offs     = (int*)alloc((size_t)(n + 1) * 4);
  int*      cursor   = (int*)alloc((size_t)n * 4);
  int*      partials = (int*)alloc(1024 * 4);
  int2*     cedge    = (int2*)alloc((size_t)e * 8);
  _Float16* xh       = (_Float16*)alloc((size_t)n * 128 * 2);
  _Float16* w1t      = (_Float16*)alloc(128 * 128 * 2);
  _Float16* w2t      = (_Float16*)alloc(128 * 128 * 2);
  _Float16* y        = (_Float16*)alloc((size_t)n * 128 * 2);
  _Float16* h1       = (_Float16*)alloc((size_t)n * 128 * 2);
  _Float16* h2       = (_Float16*)alloc((size_t)n * 128 * 2);

  int eb = (e + 255) / 256;
  int nb = (n + 1023) / 1024;
  int n4 = n * 128 / 4;

  // CSR build
  zero_int<<<(n + 255) / 256, 256, 0, stream>>>(deg, n);
  count_deg<<<eb, 256, 0, stream>>>(ei, deg, e);
  scan_block<<<nb, 1024, 0, stream>>>(deg, offs, partials, n);
  scan_partials<<<1, 128, 0, stream>>>(partials, nb);
  scan_add<<<(n + 256) / 256, 256, 0, stream>>>(offs, partials, cursor, n, e);
  build_csr<<<eb, 256, 0, stream>>>(ei, ew, cursor, cedge, e);

  // converts
  convert_f16<<<(n4 + 255) / 256, 256, 0, stream>>>(x, xh, n4);
  convert_wt<<<1, 256, 0, stream>>>(W1, w1t);
  convert_wt<<<1, 256, 0, stream>>>(W2, w2t);

  int gb = (n + 63) / 64;
  // layer 1: y = x@W1 ; h1 = relu(y + A y + b1)
  gemm_f16<<<gb, 256, 0, stream>>>(xh, w1t, y, n);
  spmm_relu_f16<<<(n + 3) / 4, 256, 0, stream>>>(y, offs, cedge, b1, h1, n);
  // layer 2: y = h1@W2 ; h2 = relu(y + A y + b2)
  gemm_f16<<<gb, 256, 0, stream>>>(h1, w2t, y, n);
  spmm_relu_f16<<<(n + 3) / 4, 256, 0, stream>>>(y, offs, cedge, b2, h2, n);
  // FC + log_softmax
  fc_lsm<<<(n + 127) / 128, 256, 0, stream>>>(h1, h2, Wfc, bfc, out, n);
}

// Round 3
// 568.790 us; speedup vs baseline: 1.2074x; 1.1339x over previous
//
#include <hip/hip_runtime.h>
#include <math.h>

#define NFEAT 128
#define NCLS 40
#define NPART 8

using f16x8 = __attribute__((ext_vector_type(8))) _Float16;
using f16x2 = __attribute__((ext_vector_type(2))) _Float16;
using f32x4 = __attribute__((ext_vector_type(4))) float;

// ---------------- CSR build ----------------
__global__ void zero_int(int* __restrict__ p, int n) {
  int i = blockIdx.x * 256 + threadIdx.x;
  if (i < n) p[i] = 0;
}

// dst-partitioned degree count: blocks with bid&7==p handle dst range p.
// Localizes atomics to one XCD's L2 (round-robin block->XCD dispatch).
__global__ __launch_bounds__(256) void count_deg_part(const int* __restrict__ ei,
    int* __restrict__ deg, int e, int n) {
  int part = blockIdx.x & 7;
  int grp = blockIdx.x >> 3;
  int ngrp = gridDim.x >> 3;
  int chunk = (n + NPART - 1) / NPART;
  int lo = part * chunk, hi = min(n, lo + chunk);
  for (int i = grp * 256 + threadIdx.x; i < e; i += ngrp * 256) {
    int d = ei[e + i];
    if (d >= lo && d < hi) atomicAdd(&deg[d], 1);
  }
}

__global__ __launch_bounds__(1024) void scan_block(const int* __restrict__ deg,
    int* __restrict__ offs, int* __restrict__ partials, int n) {
  __shared__ int s[1024];
  int t = threadIdx.x;
  int i = blockIdx.x * 1024 + t;
  int v = (i < n) ? deg[i] : 0;
  s[t] = v;
  __syncthreads();
  int val = v;
  for (int d = 1; d < 1024; d <<= 1) {
    int other = (t >= d) ? s[t - d] : 0;
    __syncthreads();
    val += other;
    s[t] = val;
    __syncthreads();
  }
  if (i < n) offs[i] = val - v;              // exclusive within block
  if (t == 1023) partials[blockIdx.x] = val; // block total
}

__global__ __launch_bounds__(128) void scan_partials(int* __restrict__ partials, int nb) {
  __shared__ int s[128];
  int t = threadIdx.x;
  int v = (t < nb) ? partials[t] : 0;
  s[t] = v;
  __syncthreads();
  int val = v;
  for (int d = 1; d < 128; d <<= 1) {
    int other = (t >= d) ? s[t - d] : 0;
    __syncthreads();
    val += other;
    s[t] = val;
    __syncthreads();
  }
  if (t < nb) partials[t] = val - v;
}

__global__ void scan_add(int* __restrict__ offs, const int* __restrict__ partials,
    int* __restrict__ cursor, int n, int e) {
  int i = blockIdx.x * 256 + threadIdx.x;
  if (i < n) {
    int o = offs[i] + partials[i >> 10];
    offs[i] = o;
    cursor[i] = o;
  } else if (i == n) {
    offs[n] = e;
  }
}

// dst-partitioned CSR fill: partition p's cedge region (~1.6MB) is written
// only by XCD p's blocks -> partial 8B writes merge into full lines in L2,
// written back once (was 8x write amplification, 100MB -> ~13MB).
__global__ __launch_bounds__(256) void build_csr_part(const int* __restrict__ ei,
    const float* __restrict__ ew, int* __restrict__ cursor,
    int2* __restrict__ cedge, int e, int n) {
  int part = blockIdx.x & 7;
  int grp = blockIdx.x >> 3;
  int ngrp = gridDim.x >> 3;
  int chunk = (n + NPART - 1) / NPART;
  int lo = part * chunk, hi = min(n, lo + chunk);
  for (int i = grp * 256 + threadIdx.x; i < e; i += ngrp * 256) {
    int d = ei[e + i];
    if (d >= lo && d < hi) {
      int s = ei[i];
      float w = ew[i];
      int p = atomicAdd(&cursor[d], 1);
      cedge[p] = make_int2(s, __float_as_int(w));
    }
  }
}

// ---------------- fp32 -> fp16 converts ----------------
__global__ void convert_f16(const float* __restrict__ X, _Float16* __restrict__ Xh, int n4) {
  int i = blockIdx.x * 256 + threadIdx.x;
  if (i < n4) {
    float4 v = ((const float4*)X)[i];
    f16x2 a, b;
    a.x = (_Float16)v.x; a.y = (_Float16)v.y;
    b.x = (_Float16)v.z; b.y = (_Float16)v.w;
    ((f16x2*)Xh)[i * 2] = a;
    ((f16x2*)Xh)[i * 2 + 1] = b;
  }
}

__global__ void convert_wt(const float* __restrict__ W, _Float16* __restrict__ Wt) {
  // Wt[c][k] = fp16(W[k][c]), 128x128
  int t = threadIdx.x;
  for (int i = t; i < 128 * 128; i += 256) {
    int c = i >> 7, k = i & 127;
    Wt[i] = (_Float16)W[k * 128 + c];
  }
}

// ------- MFMA GEMM: Y[n,128](f16) = Xh[n,128](f16) @ W (Wt = W^T, f16) -------
__global__ __launch_bounds__(256) void gemm_f16(const _Float16* __restrict__ Xh,
    const _Float16* __restrict__ Wt, _Float16* __restrict__ Y, int n) {
  __shared__ _Float16 Ys[64][136];   // bounce for coalesced stores
  int t = threadIdx.x;
  int wv = t >> 6, l = t & 63;
  int r0 = blockIdx.x * 64 + wv * 16;
  int arow = r0 + (l & 15);
  int kq = (l >> 4) * 8;
  bool rowok = arow < n;
  f32x4 acc[8] = {};
  for (int kc = 0; kc < 128; kc += 32) {
    f16x8 a = {};
    if (rowok) a = *(const f16x8*)(Xh + (size_t)arow * 128 + kc + kq);
    #pragma unroll
    for (int j = 0; j < 8; j++) {
      f16x8 b = *(const f16x8*)(Wt + (size_t)(j * 16 + (l & 15)) * 128 + kc + kq);
      acc[j] = __builtin_amdgcn_mfma_f32_16x16x32_f16(a, b, acc[j], 0, 0, 0);
    }
  }
  #pragma unroll
  for (int j = 0; j < 8; j++)
    #pragma unroll
    for (int i = 0; i < 4; i++)
      Ys[wv * 16 + (l >> 4) * 4 + i][j * 16 + (l & 15)] = (_Float16)acc[j][i];
  __syncthreads();
  int r = t >> 2;
  int c0 = (t & 3) * 32;
  int grow = blockIdx.x * 64 + r;
  if (grow < n) {
    #pragma unroll
    for (int i = 0; i < 4; i++) {
      f16x8 v = *(const f16x8*)&Ys[r][c0 + i * 8];
      *(f16x8*)(Y + (size_t)grow * 128 + c0 + i * 8) = v;
    }
  }
}

// -- SpMM + self + bias + ReLU (fp16 rows, fp32 accum): H = relu(Y + A Y + b) --
__global__ __launch_bounds__(256) void spmm_relu_f16(const _Float16* __restrict__ Y,
    const int* __restrict__ offs, const int2* __restrict__ cedge,
    const float* __restrict__ bias, _Float16* __restrict__ H, int n) {
  int wv = threadIdx.x >> 6;
  int lane = threadIdx.x & 63;
  int node = blockIdx.x * 4 + wv;          // one wave per dst node
  if (node >= n) return;
  int c = lane * 2;                        // 2 channels/lane -> 256B/wave gathers
  const _Float16* Yc = Y + c;
  int e0 = offs[node], e1 = offs[node + 1];
  float ax0 = 0.f, ay0 = 0.f, ax1 = 0.f, ay1 = 0.f;
  float ax2 = 0.f, ay2 = 0.f, ax3 = 0.f, ay3 = 0.f;
  int e = e0;
  for (; e + 3 < e1; e += 4) {             // 4 gathers in flight
    int2 p0 = cedge[e];
    int2 p1 = cedge[e + 1];
    int2 p2 = cedge[e + 2];
    int2 p3 = cedge[e + 3];
    f16x2 v0 = *(const f16x2*)(Yc + (size_t)p0.x * 128);
    f16x2 v1 = *(const f16x2*)(Yc + (size_t)p1.x * 128);
    f16x2 v2 = *(const f16x2*)(Yc + (size_t)p2.x * 128);
    f16x2 v3 = *(const f16x2*)(Yc + (size_t)p3.x * 128);
    float w0 = __int_as_float(p0.y), w1 = __int_as_float(p1.y);
    float w2 = __int_as_float(p2.y), w3 = __int_as_float(p3.y);
    ax0 = fmaf(w0, (float)v0.x, ax0); ay0 = fmaf(w0, (float)v0.y, ay0);
    ax1 = fmaf(w1, (float)v1.x, ax1); ay1 = fmaf(w1, (float)v1.y, ay1);
    ax2 = fmaf(w2, (float)v2.x, ax2); ay2 = fmaf(w2, (float)v2.y, ay2);
    ax3 = fmaf(w3, (float)v3.x, ax3); ay3 = fmaf(w3, (float)v3.y, ay3);
  }
  for (; e < e1; e++) {
    int2 p0 = cedge[e];
    f16x2 v0 = *(const f16x2*)(Yc + (size_t)p0.x * 128);
    float w0 = __int_as_float(p0.y);
    ax0 = fmaf(w0, (float)v0.x, ax0); ay0 = fmaf(w0, (float)v0.y, ay0);
  }
  f16x2 yv = *(const f16x2*)(Yc + (size_t)node * 128);
  float2 bv = *(const float2*)(bias + c);
  float zx = (float)yv.x + (ax0 + ax1) + (ax2 + ax3) + bv.x;
  float zy = (float)yv.y + (ay0 + ay1) + (ay2 + ay3) + bv.y;
  f16x2 o;
  o.x = (_Float16)fmaxf(zx, 0.f);
  o.y = (_Float16)fmaxf(zy, 0.f);
  *(f16x2*)(H + (size_t)node * 128 + c) = o;
}

// -------- FC over concat(h1,h2)(f16) + log_softmax (fp32 compute) --------
__global__ __launch_bounds__(256) void fc_lsm(const _Float16* __restrict__ H1,
    const _Float16* __restrict__ H2, const float* __restrict__ Wfc,
    const float* __restrict__ bfc, float* __restrict__ out, int n) {
  __shared__ float Wl[256 * NCLS];        // 40 KB, [k][c] layout
  __shared__ float Hs[64][132];           // 33 KB, transposed chunk Hs[k][r]
  int t = threadIdx.x;
  for (int i = t; i < 256 * NCLS; i += 256) Wl[i] = Wfc[i];
  int tx = t & 7, ty = t >> 3;            // tx: 5-col group (8x5=40), ty: 4-row group
  int row0 = blockIdx.x * 128;
  float acc[4][5] = {};
  for (int kc = 0; kc < 256; kc += 64) {
    { // stage 128 rows x 64 k of concat(H1,H2), transposed, f16 -> f32
      int r = t & 127;
      int half = t >> 7;
      int row = row0 + r;
      const _Float16* src = (kc < 128)
          ? (H1 + (size_t)row * 128 + kc + half * 32)
          : (H2 + (size_t)row * 128 + (kc - 128) + half * 32);
      if (row < n) {
        #pragma unroll
        for (int i = 0; i < 4; i++) {
          f16x8 v = ((const f16x8*)src)[i];
          #pragma unroll
          for (int q = 0; q < 8; q++) Hs[half * 32 + i * 8 + q][r] = (float)v[q];
        }
      } else {
        #pragma unroll
        for (int k = 0; k < 32; k++) Hs[half * 32 + k][r] = 0.f;
      }
    }
    __syncthreads();
    #pragma unroll 4
    for (int k = 0; k < 64; k++) {
      float4 a = *(const float4*)&Hs[k][ty * 4];
      const float* wrow = &Wl[(kc + k) * NCLS + tx * 5];
      float b_[5];
      #pragma unroll
      for (int j = 0; j < 5; j++) b_[j] = wrow[j];
      #pragma unroll
      for (int j = 0; j < 5; j++) {
        acc[0][j] = fmaf(a.x, b_[j], acc[0][j]);
        acc[1][j] = fmaf(a.y, b_[j], acc[1][j]);
        acc[2][j] = fmaf(a.z, b_[j], acc[2][j]);
        acc[3][j] = fmaf(a.w, b_[j], acc[3][j]);
      }
    }
    __syncthreads();
  }
  int c0 = tx * 5;
  float bv[5];
  #pragma unroll
  for (int j = 0; j < 5; j++) bv[j] = bfc[c0 + j];
  #pragma unroll
  for (int i = 0; i < 4; i++) {
    float lg[5];
    #pragma unroll
    for (int j = 0; j < 5; j++) lg[j] = acc[i][j] + bv[j];
    float m = lg[0];
    #pragma unroll
    for (int j = 1; j < 5; j++) m = fmaxf(m, lg[j]);
    m = fmaxf(m, __shfl_xor(m, 1));
    m = fmaxf(m, __shfl_xor(m, 2));
    m = fmaxf(m, __shfl_xor(m, 4));       // 8 lanes (same ty) own one row's 40 cols
    float ssum = 0.f;
    #pragma unroll
    for (int j = 0; j < 5; j++) ssum += __expf(lg[j] - m);
    ssum += __shfl_xor(ssum, 1);
    ssum += __shfl_xor(ssum, 2);
    ssum += __shfl_xor(ssum, 4);
    float lse = m + __logf(ssum);
    int row = row0 + ty * 4 + i;
    if (row < n) {
      #pragma unroll
      for (int j = 0; j < 5; j++) out[(size_t)row * NCLS + c0 + j] = lg[j] - lse;
    }
  }
}

extern "C" void kernel_launch(void* const* d_in, const int* in_sizes, int n_in,
                              void* d_out, int out_size, void* d_ws, size_t ws_size,
                              hipStream_t stream) {
  const float* x   = (const float*)d_in[0];
  const int*   ei  = (const int*)d_in[1];
  const float* ew  = (const float*)d_in[2];
  const float* W1  = (const float*)d_in[3];
  const float* b1  = (const float*)d_in[4];
  const float* W2  = (const float*)d_in[5];
  const float* b2  = (const float*)d_in[6];
  const float* Wfc = (const float*)d_in[7];
  const float* bfc = (const float*)d_in[8];
  float* out = (float*)d_out;
  int n = in_sizes[0] / NFEAT;   // 100000
  int e = in_sizes[2];           // 1600000

  // workspace partition (~116 MB)
  char* ws = (char*)d_ws;
  size_t off = 0;
  auto alloc = [&](size_t bytes) -> void* {
    void* p = ws + off; off += (bytes + 255) & ~(size_t)255; return p;
  };
  int*      deg      = (int*)alloc((size_t)n * 4);
  int*      offs     = (int*)alloc((size_t)(n + 1) * 4);
  int*      cursor   = (int*)alloc((size_t)n * 4);
  int*      partials = (int*)alloc(1024 * 4);
  int2*     cedge    = (int2*)alloc((size_t)e * 8);
  _Float16* xh       = (_Float16*)alloc((size_t)n * 128 * 2);
  _Float16* w1t      = (_Float16*)alloc(128 * 128 * 2);
  _Float16* w2t      = (_Float16*)alloc(128 * 128 * 2);
  _Float16* y        = (_Float16*)alloc((size_t)n * 128 * 2);
  _Float16* h1       = (_Float16*)alloc((size_t)n * 128 * 2);
  _Float16* h2       = (_Float16*)alloc((size_t)n * 128 * 2);

  int nb = (n + 1023) / 1024;
  int n4 = n * 128 / 4;
  int pb = 8 * 104;   // 8 dst-partitions x 104 blocks each

  // CSR build (dst-partitioned counting sort)
  zero_int<<<(n + 255) / 256, 256, 0, stream>>>(deg, n);
  count_deg_part<<<pb, 256, 0, stream>>>(ei, deg, e, n);
  scan_block<<<nb, 1024, 0, stream>>>(deg, offs, partials, n);
  scan_partials<<<1, 128, 0, stream>>>(partials, nb);
  scan_add<<<(n + 256) / 256, 256, 0, stream>>>(offs, partials, cursor, n, e);
  build_csr_part<<<pb, 256, 0, stream>>>(ei, ew, cursor, cedge, e, n);

  // converts
  convert_f16<<<(n4 + 255) / 256, 256, 0, stream>>>(x, xh, n4);
  convert_wt<<<1, 256, 0, stream>>>(W1, w1t);
  convert_wt<<<1, 256, 0, stream>>>(W2, w2t);

  int gb = (n + 63) / 64;
  // layer 1: y = x@W1 ; h1 = relu(y + A y + b1)
  gemm_f16<<<gb, 256, 0, stream>>>(xh, w1t, y, n);
  spmm_relu_f16<<<(n + 3) / 4, 256, 0, stream>>>(y, offs, cedge, b1, h1, n);
  // layer 2: y = h1@W2 ; h2 = relu(y + A y + b2)
  gemm_f16<<<gb, 256, 0, stream>>>(h1, w2t, y, n);
  spmm_relu_f16<<<(n + 3) / 4, 256, 0, stream>>>(y, offs, cedge, b2, h2, n);
  // FC + log_softmax
  fc_lsm<<<(n + 127) / 128, 256, 0, stream>>>(h1, h2, Wfc, bfc, out, n);
}